// Round 14
// baseline (46.924 us; speedup 1.0000x reference)
//
#include <hip/hip_runtime.h>

typedef __bf16 bf16x8 __attribute__((ext_vector_type(8)));
typedef float f32x16 __attribute__((ext_vector_type(16)));

#define BLK      256
#define WPB      4                  // waves per block
#define TPW      2                  // own tiles per wave (1 LDS read feeds 2 MFMAs)
#define TPB      (WPB * TPW)        // 8 own tiles per block
#define CH_TILES 40                 // stream tiles per block: 40 KB LDS
#define CH_SLOTS (CH_TILES * 32)    // 1280 stream points per y-block

__device__ __forceinline__ float min3f(float a, float b, float c) {
    float d;
    asm("v_min3_f32 %0, %1, %2, %3" : "=v"(d) : "v"(a), "v"(b), "v"(c));
    return d;
}
// MFMA with early-clobber destination: D != {A,B,C}; zero-C stays pinned.
// NOTE: inline-asm MFMA is invisible to the compiler's hazard recognizer --
// every reader of the result MUST carry its own wait-states (see fold8).
__device__ __forceinline__ f32x16 mfma_tile(bf16x8 a, bf16x8 b, f32x16 zc) {
    f32x16 d;
    asm("v_mfma_f32_32x32x16_bf16 %0, %1, %2, %3"
        : "=&v"(d) : "v"(a), "v"(b), "v"(zc));
    return d;
}
// HAZARD-SAFE fold: single asm block, 4x s_nop 7 (32 wait-cycles >= the ~18
// required between a 16-pass MFMA write and a VALU read of its D registers)
// ahead of the 8 v_min3 reads. Safe under ANY compiler schedule; the nops
// occupy no VALU issue slots, so co-resident waves hide them. This is the fix
// for rounds 11-13: the un-padded FOLD could be scheduled <18 cyc after the
// producing asm MFMA, reading a not-yet-written D tuple (deterministic
// corruption, bit-identical across builds with identical epilogue source).
__device__ __forceinline__ void fold8(float& r0, float& r1, float& r2, float& r3,
                                      float& r4, float& r5, float& r6, float& r7,
                                      f32x16 d) {
    asm("s_nop 7\n\t"
        "s_nop 7\n\t"
        "s_nop 7\n\t"
        "s_nop 7\n\t"
        "v_min3_f32 %0, %8,  %9,  %0\n\t"
        "v_min3_f32 %1, %10, %11, %1\n\t"
        "v_min3_f32 %2, %12, %13, %2\n\t"
        "v_min3_f32 %3, %14, %15, %3\n\t"
        "v_min3_f32 %4, %16, %17, %4\n\t"
        "v_min3_f32 %5, %18, %19, %5\n\t"
        "v_min3_f32 %6, %20, %21, %6\n\t"
        "v_min3_f32 %7, %22, %23, %7"
        : "+v"(r0), "+v"(r1), "+v"(r2), "+v"(r3),
          "+v"(r4), "+v"(r5), "+v"(r6), "+v"(r7)
        : "v"(d[0]),  "v"(d[1]),  "v"(d[2]),  "v"(d[3]),
          "v"(d[4]),  "v"(d[5]),  "v"(d[6]),  "v"(d[7]),
          "v"(d[8]),  "v"(d[9]),  "v"(d[10]), "v"(d[11]),
          "v"(d[12]), "v"(d[13]), "v"(d[14]), "v"(d[15]));
}
#define FOLD(rm, dv) fold8(rm[0], rm[1], rm[2], rm[3], rm[4], rm[5], rm[6], rm[7], dv)

// Order-preserving float -> uint key: min over keys == min over floats.
__device__ __forceinline__ unsigned int f2key(float f) {
    unsigned int b = __float_as_uint(f);
    return (b & 0x80000000u) ? ~b : (b | 0x80000000u);
}
__device__ __forceinline__ float key2f(unsigned int k) {
    unsigned int b = (k & 0x80000000u) ? (k ^ 0x80000000u) : ~k;
    return __uint_as_float(b);
}
// hi/lo bf16 split of a point + its |s|^2.
__device__ __forceinline__ void splitp(float x, float y, float z,
    __bf16& xh, __bf16& xl, __bf16& yh, __bf16& yl,
    __bf16& zh, __bf16& zl, __bf16& s2h, __bf16& s2l)
{
    float s2 = fmaf(x, x, fmaf(y, y, z*z));
    xh = (__bf16)x;  xl = (__bf16)(x - (float)xh);
    yh = (__bf16)y;  yl = (__bf16)(y - (float)yh);
    zh = (__bf16)z;  zl = (__bf16)(z - (float)zh);
    s2h = (__bf16)s2; s2l = (__bf16)(s2 - (float)s2h);
}

// d2 = p2 + g2 - 2<p,g> via mfma_f32_32x32x16_bf16, split-bf16 K recipe
// (A=stream | B=own):  k0:1|p2h k1:1|p2l k2:g2h|1 k3:g2l|1
//   x: k4:gxh|-2pxh k5:gxl|-2pxh k6:gxh|-2pxl  (y: k7-9, z: k10-12; 13-15: 0)
// exact to ~2^-17. Geometry is EXACTLY the round-10 build that passed twice;
// the only change this round is the hazard-safe fold8 (one variable).
__global__ __launch_bounds__(BLK, 4) void chamfer_mfma(
    const float* __restrict__ pred, const float* __restrict__ gt,
    unsigned int* __restrict__ minsAll, int nP, int nG)
{
    __shared__ bf16x8 sh[CH_TILES * 64];

    const int dir  = blockIdx.z;            // 0: own pred / stream gt
    const int nOwn = dir ? nG : nP;
    const int nStr = dir ? nP : nG;
    const int ownTiles = (nOwn + 31) >> 5;
    unsigned int* mins = minsAll + (dir ? nP : 0);

    const int tid = threadIdx.x, wave = tid >> 6, lane = tid & 63, col = lane & 31;
    const __bf16 one = (__bf16)1.0f, zero = (__bf16)0.0f, big = (__bf16)1.0e30f;

    // ---- stage CH_TILES stream tiles into LDS in A-layout, from raw input ----
    #pragma unroll
    for (int j = tid; j < CH_SLOTS; j += BLK) {
        const int g = blockIdx.y * CH_SLOTS + j;
        float x = 0.f, y = 0.f, z = 0.f;
        const bool v = g < nStr;
        if (v) {
            if (dir == 0) { float4 G = ((const float4*)gt)[g]; x = G.x; y = G.y; z = G.z; }
            else          { x = pred[3*g]; y = pred[3*g+1]; z = pred[3*g+2]; }
        }
        __bf16 xh, xl, yh, yl, zh, zl, s2h, s2l;
        splitp(x, y, z, xh, xl, yh, yl, zh, zl, s2h, s2l);
        if (!v) { s2h = big; s2l = big; }     // pad: d2 ~ 2e30, never wins
        const int t = j >> 5, q = j & 31;
        sh[t*64 + q]      = bf16x8{one, one, s2h, s2l, xh, xl, xh, yh};
        sh[t*64 + 32 + q] = bf16x8{yl, yh, zh, zl, zh, zero, zero, zero};
    }

    // ---- B fragments for the wave's two own tiles (from raw input) ----
    const int tileA = blockIdx.x * TPB + wave * TPW;
    const int tileB = tileA + 1;
    bf16x8 bf0, bf1;
    {
        auto mk = [&](int tile) -> bf16x8 {
            int i = tile * 32 + col; i = min(i, nOwn - 1);   // clamp: dummy work
            float x, y, z;
            if (dir == 0) { x = pred[3*i]; y = pred[3*i+1]; z = pred[3*i+2]; }
            else          { float4 G = ((const float4*)gt)[i]; x = G.x; y = G.y; z = G.z; }
            __bf16 xh, xl, yh, yl, zh, zl, q2h, q2l;
            splitp(x, y, z, xh, xl, yh, yl, zh, zl, q2h, q2l);
            const __bf16 m2xh = (__bf16)(-2.f*(float)xh), m2xl = (__bf16)(-2.f*(float)xl);
            const __bf16 m2yh = (__bf16)(-2.f*(float)yh), m2yl = (__bf16)(-2.f*(float)yl);
            const __bf16 m2zh = (__bf16)(-2.f*(float)zh), m2zl = (__bf16)(-2.f*(float)zl);
            return (lane < 32)
                ? bf16x8{q2h, q2l, one, one, m2xh, m2xh, m2xl, m2yh}
                : bf16x8{m2yh, m2yl, m2zh, m2zh, m2zl, zero, zero, zero};
        };
        bf0 = mk(tileA);
        bf1 = mk(tileB);
    }
    __syncthreads();

    float rm0[8], rm1[8];
    #pragma unroll
    for (int j = 0; j < 8; ++j) { rm0[j] = 3.0e38f; rm1[j] = 3.0e38f; }
    f32x16 zc = {};   // pinned zero-C

    // prologue: 2 stream tiles in flight (4 MFMAs)
    bf16x8 aA = sh[lane];
    f32x16 d00 = mfma_tile(aA, bf0, zc);
    f32x16 d01 = mfma_tile(aA, bf1, zc);
    bf16x8 aB = sh[64 + lane];
    f32x16 d10 = mfma_tile(aB, bf0, zc);
    f32x16 d11 = mfma_tile(aB, bf1, zc);

    #pragma unroll
    for (int t = 2; t < CH_TILES; t += 2) {
        bf16x8 a0 = sh[t*64 + lane];
        FOLD(rm0, d00); FOLD(rm1, d01);          // fold tiles issued 4 MFMAs ago
        d00 = mfma_tile(a0, bf0, zc);
        d01 = mfma_tile(a0, bf1, zc);
        bf16x8 a1 = sh[(t+1)*64 + lane];
        FOLD(rm0, d10); FOLD(rm1, d11);
        d10 = mfma_tile(a1, bf0, zc);
        d11 = mfma_tile(a1, bf1, zc);
    }
    FOLD(rm0, d00); FOLD(rm1, d01);
    FOLD(rm0, d10); FOLD(rm1, d11);

    float mA, mB;
    { float a = min3f(rm0[0], rm0[1], rm0[2]);
      float b = min3f(rm0[3], rm0[4], rm0[5]);
      float c = min3f(rm0[6], rm0[7], a);
      mA = fminf(fminf(b, c), 3.0e38f); }        // also NaN-sanitizes
    { float a = min3f(rm1[0], rm1[1], rm1[2]);
      float b = min3f(rm1[3], rm1[4], rm1[5]);
      float c = min3f(rm1[6], rm1[7], a);
      mB = fminf(fminf(b, c), 3.0e38f); }

    const int idxA = tileA * 32 + col;
    const int idxB = tileB * 32 + col;
    if (tileA < ownTiles && idxA < nOwn) atomicMin(&mins[idxA], f2key(mA));
    if (tileB < ownTiles && idxB < nOwn) atomicMin(&mins[idxB], f2key(mB));
}

// Stage 1: per-block partial sums (scaled). Untouched keys decode to 1e30 so
// a non-running min kernel shows as a HUGE error, not a silent 0.
__global__ __launch_bounds__(BLK) void chamfer_reduce1(
    const unsigned int* __restrict__ mins, float* __restrict__ part,
    int nP, int nG, float invP, float invG)
{
    const int i = blockIdx.x * BLK + threadIdx.x;
    float v = 0.f;
    if (i < nP + nG) {
        const unsigned int k = mins[i];
        const float d = (k == 0xFFFFFFFFu) ? 1.0e30f : fmaxf(0.f, key2f(k));
        v = d * (i < nP ? invP : invG);
    }
    #pragma unroll
    for (int o = 32; o > 0; o >>= 1) v += __shfl_xor(v, o);
    __shared__ float r[WPB];
    const int wid = threadIdx.x >> 6, lane = threadIdx.x & 63;
    if (lane == 0) r[wid] = v;
    __syncthreads();
    if (threadIdx.x == 0) part[blockIdx.x] = r[0] + r[1] + r[2] + r[3];
}

// Stage 2: one block, fixed-order deterministic sum of the partials.
__global__ __launch_bounds__(BLK) void chamfer_reduce2(
    const float* __restrict__ part, float* __restrict__ out, int nPart)
{
    float v = 0.f;
    for (int i = threadIdx.x; i < nPart; i += BLK) v += part[i];
    #pragma unroll
    for (int o = 32; o > 0; o >>= 1) v += __shfl_xor(v, o);
    __shared__ float r[WPB];
    const int wid = threadIdx.x >> 6, lane = threadIdx.x & 63;
    if (lane == 0) r[wid] = v;
    __syncthreads();
    if (threadIdx.x == 0) out[0] = r[0] + r[1] + r[2] + r[3];
}

extern "C" void kernel_launch(void* const* d_in, const int* in_sizes, int n_in,
                              void* d_out, int out_size, void* d_ws, size_t ws_size,
                              hipStream_t stream)
{
    const float* pred = (const float*)d_in[0];
    const float* gt   = (const float*)d_in[1];
    const int nP = in_sizes[0] / 3;
    const int nG = in_sizes[1] / 4;
    const int nTot = nP + nG;

    unsigned int* mins = (unsigned int*)d_ws;                       // nTot keys
    const int nPart = (nTot + BLK - 1) / BLK;                       // 157
    float* part = (float*)((char*)d_ws + (((size_t)nTot * 4 + 255) & ~(size_t)255));
    (void)ws_size; (void)n_in; (void)out_size;

    hipMemsetAsync(mins, 0xFF, (size_t)nTot * 4, stream);           // keys = +inf

    const int maxN = nP > nG ? nP : nG;
    const int tilesMax = (maxN + 31) / 32;                          // 625
    dim3 grid((tilesMax + TPB - 1) / TPB,                           // 79
              (maxN + CH_SLOTS - 1) / CH_SLOTS,                     // 16
              2);
    chamfer_mfma<<<grid, BLK, 0, stream>>>(pred, gt, mins, nP, nG);

    chamfer_reduce1<<<nPart, BLK, 0, stream>>>(mins, part, nP, nG,
                                               1.0f / (float)nP, 1.0f / (float)nG);
    chamfer_reduce2<<<1, BLK, 0, stream>>>(part, (float*)d_out, nPart);
}

// Round 15
// 44.961 us; speedup vs baseline: 1.0437x; 1.0437x over previous
//
#include <hip/hip_runtime.h>

typedef __bf16 bf16x8 __attribute__((ext_vector_type(8)));
typedef float f32x16 __attribute__((ext_vector_type(16)));

#define BLK      256
#define WPB      4                  // waves per block
#define TPW      2                  // own tiles per wave (1 LDS read feeds 2 MFMAs)
#define TPB      (WPB * TPW)        // 8 own tiles per block
#define CH_TILES 20                 // stream tiles per block: 20 KB LDS -> 8 blocks/CU
#define CH_SLOTS (CH_TILES * 32)    // 640 stream points per y-block

__device__ __forceinline__ float min3f(float a, float b, float c) {
    float d;
    asm("v_min3_f32 %0, %1, %2, %3" : "=v"(d) : "v"(a), "v"(b), "v"(c));
    return d;
}
// MFMA with early-clobber destination: D != {A,B,C}; zero-C stays pinned.
// NOTE: inline-asm MFMA is invisible to the compiler's hazard recognizer --
// every reader of the result MUST carry its own wait-states (see fold8).
__device__ __forceinline__ f32x16 mfma_tile(bf16x8 a, bf16x8 b, f32x16 zc) {
    f32x16 d;
    asm("v_mfma_f32_32x32x16_bf16 %0, %1, %2, %3"
        : "=&v"(d) : "v"(a), "v"(b), "v"(zc));
    return d;
}
// HAZARD-SAFE fold: single asm block, 4x s_nop 7 (32 wait-cycles >= the ~18
// required between a 16-pass MFMA write and a VALU read of its D registers)
// ahead of the 8 v_min3 reads. Safe under ANY compiler schedule (this fixed
// rounds 11-13's deterministic corruption); nops are hidden by other waves.
__device__ __forceinline__ void fold8(float& r0, float& r1, float& r2, float& r3,
                                      float& r4, float& r5, float& r6, float& r7,
                                      f32x16 d) {
    asm("s_nop 7\n\t"
        "s_nop 7\n\t"
        "s_nop 7\n\t"
        "s_nop 7\n\t"
        "v_min3_f32 %0, %8,  %9,  %0\n\t"
        "v_min3_f32 %1, %10, %11, %1\n\t"
        "v_min3_f32 %2, %12, %13, %2\n\t"
        "v_min3_f32 %3, %14, %15, %3\n\t"
        "v_min3_f32 %4, %16, %17, %4\n\t"
        "v_min3_f32 %5, %18, %19, %5\n\t"
        "v_min3_f32 %6, %20, %21, %6\n\t"
        "v_min3_f32 %7, %22, %23, %7"
        : "+v"(r0), "+v"(r1), "+v"(r2), "+v"(r3),
          "+v"(r4), "+v"(r5), "+v"(r6), "+v"(r7)
        : "v"(d[0]),  "v"(d[1]),  "v"(d[2]),  "v"(d[3]),
          "v"(d[4]),  "v"(d[5]),  "v"(d[6]),  "v"(d[7]),
          "v"(d[8]),  "v"(d[9]),  "v"(d[10]), "v"(d[11]),
          "v"(d[12]), "v"(d[13]), "v"(d[14]), "v"(d[15]));
}
#define FOLD(rm, dv) fold8(rm[0], rm[1], rm[2], rm[3], rm[4], rm[5], rm[6], rm[7], dv)

// Order-preserving float -> uint key: min over keys == min over floats.
__device__ __forceinline__ unsigned int f2key(float f) {
    unsigned int b = __float_as_uint(f);
    return (b & 0x80000000u) ? ~b : (b | 0x80000000u);
}
__device__ __forceinline__ float key2f(unsigned int k) {
    unsigned int b = (k & 0x80000000u) ? (k ^ 0x80000000u) : ~k;
    return __uint_as_float(b);
}
// hi/lo bf16 split of a point + its |s|^2.
__device__ __forceinline__ void splitp(float x, float y, float z,
    __bf16& xh, __bf16& xl, __bf16& yh, __bf16& yl,
    __bf16& zh, __bf16& zl, __bf16& s2h, __bf16& s2l)
{
    float s2 = fmaf(x, x, fmaf(y, y, z*z));
    xh = (__bf16)x;  xl = (__bf16)(x - (float)xh);
    yh = (__bf16)y;  yl = (__bf16)(y - (float)yh);
    zh = (__bf16)z;  zl = (__bf16)(z - (float)zh);
    s2h = (__bf16)s2; s2l = (__bf16)(s2 - (float)s2h);
}

// d2 = p2 + g2 - 2<p,g> via mfma_f32_32x32x16_bf16, split-bf16 K recipe
// (A=stream | B=own):  k0:1|p2h k1:1|p2l k2:g2h|1 k3:g2l|1
//   x: k4:gxh|-2pxh k5:gxl|-2pxh k6:gxh|-2pxl  (y: k7-9, z: k10-12; 13-15: 0)
// exact to ~2^-17. Same code as the round-14 build that passed (absmax 0.0);
// single change: CH_TILES 40->20 (20 KB LDS -> 8 blocks/CU = 32 waves/CU),
// now safe because fold8 carries its own MFMA-read wait-states.
__global__ __launch_bounds__(BLK, 4) void chamfer_mfma(
    const float* __restrict__ pred, const float* __restrict__ gt,
    unsigned int* __restrict__ minsAll, int nP, int nG)
{
    __shared__ bf16x8 sh[CH_TILES * 64];

    const int dir  = blockIdx.z;            // 0: own pred / stream gt
    const int nOwn = dir ? nG : nP;
    const int nStr = dir ? nP : nG;
    const int ownTiles = (nOwn + 31) >> 5;
    unsigned int* mins = minsAll + (dir ? nP : 0);

    const int tid = threadIdx.x, wave = tid >> 6, lane = tid & 63, col = lane & 31;
    const __bf16 one = (__bf16)1.0f, zero = (__bf16)0.0f, big = (__bf16)1.0e30f;

    // ---- stage CH_TILES stream tiles into LDS in A-layout, from raw input ----
    #pragma unroll
    for (int j = tid; j < CH_SLOTS; j += BLK) {
        const int g = blockIdx.y * CH_SLOTS + j;
        float x = 0.f, y = 0.f, z = 0.f;
        const bool v = g < nStr;
        if (v) {
            if (dir == 0) { float4 G = ((const float4*)gt)[g]; x = G.x; y = G.y; z = G.z; }
            else          { x = pred[3*g]; y = pred[3*g+1]; z = pred[3*g+2]; }
        }
        __bf16 xh, xl, yh, yl, zh, zl, s2h, s2l;
        splitp(x, y, z, xh, xl, yh, yl, zh, zl, s2h, s2l);
        if (!v) { s2h = big; s2l = big; }     // pad: d2 ~ 2e30, never wins
        const int t = j >> 5, q = j & 31;
        sh[t*64 + q]      = bf16x8{one, one, s2h, s2l, xh, xl, xh, yh};
        sh[t*64 + 32 + q] = bf16x8{yl, yh, zh, zl, zh, zero, zero, zero};
    }

    // ---- B fragments for the wave's two own tiles (from raw input) ----
    const int tileA = blockIdx.x * TPB + wave * TPW;
    const int tileB = tileA + 1;
    bf16x8 bf0, bf1;
    {
        auto mk = [&](int tile) -> bf16x8 {
            int i = tile * 32 + col; i = min(i, nOwn - 1);   // clamp: dummy work
            float x, y, z;
            if (dir == 0) { x = pred[3*i]; y = pred[3*i+1]; z = pred[3*i+2]; }
            else          { float4 G = ((const float4*)gt)[i]; x = G.x; y = G.y; z = G.z; }
            __bf16 xh, xl, yh, yl, zh, zl, q2h, q2l;
            splitp(x, y, z, xh, xl, yh, yl, zh, zl, q2h, q2l);
            const __bf16 m2xh = (__bf16)(-2.f*(float)xh), m2xl = (__bf16)(-2.f*(float)xl);
            const __bf16 m2yh = (__bf16)(-2.f*(float)yh), m2yl = (__bf16)(-2.f*(float)yl);
            const __bf16 m2zh = (__bf16)(-2.f*(float)zh), m2zl = (__bf16)(-2.f*(float)zl);
            return (lane < 32)
                ? bf16x8{q2h, q2l, one, one, m2xh, m2xh, m2xl, m2yh}
                : bf16x8{m2yh, m2yl, m2zh, m2zh, m2zl, zero, zero, zero};
        };
        bf0 = mk(tileA);
        bf1 = mk(tileB);
    }
    __syncthreads();

    float rm0[8], rm1[8];
    #pragma unroll
    for (int j = 0; j < 8; ++j) { rm0[j] = 3.0e38f; rm1[j] = 3.0e38f; }
    f32x16 zc = {};   // pinned zero-C

    // prologue: 2 stream tiles in flight (4 MFMAs)
    bf16x8 aA = sh[lane];
    f32x16 d00 = mfma_tile(aA, bf0, zc);
    f32x16 d01 = mfma_tile(aA, bf1, zc);
    bf16x8 aB = sh[64 + lane];
    f32x16 d10 = mfma_tile(aB, bf0, zc);
    f32x16 d11 = mfma_tile(aB, bf1, zc);

    #pragma unroll
    for (int t = 2; t < CH_TILES; t += 2) {
        bf16x8 a0 = sh[t*64 + lane];
        FOLD(rm0, d00); FOLD(rm1, d01);          // fold tiles issued 4 MFMAs ago
        d00 = mfma_tile(a0, bf0, zc);
        d01 = mfma_tile(a0, bf1, zc);
        bf16x8 a1 = sh[(t+1)*64 + lane];
        FOLD(rm0, d10); FOLD(rm1, d11);
        d10 = mfma_tile(a1, bf0, zc);
        d11 = mfma_tile(a1, bf1, zc);
    }
    FOLD(rm0, d00); FOLD(rm1, d01);
    FOLD(rm0, d10); FOLD(rm1, d11);

    float mA, mB;
    { float a = min3f(rm0[0], rm0[1], rm0[2]);
      float b = min3f(rm0[3], rm0[4], rm0[5]);
      float c = min3f(rm0[6], rm0[7], a);
      mA = fminf(fminf(b, c), 3.0e38f); }        // also NaN-sanitizes
    { float a = min3f(rm1[0], rm1[1], rm1[2]);
      float b = min3f(rm1[3], rm1[4], rm1[5]);
      float c = min3f(rm1[6], rm1[7], a);
      mB = fminf(fminf(b, c), 3.0e38f); }

    const int idxA = tileA * 32 + col;
    const int idxB = tileB * 32 + col;
    if (tileA < ownTiles && idxA < nOwn) atomicMin(&mins[idxA], f2key(mA));
    if (tileB < ownTiles && idxB < nOwn) atomicMin(&mins[idxB], f2key(mB));
}

// Stage 1: per-block partial sums (scaled). Untouched keys decode to 1e30 so
// a non-running min kernel shows as a HUGE error, not a silent 0.
__global__ __launch_bounds__(BLK) void chamfer_reduce1(
    const unsigned int* __restrict__ mins, float* __restrict__ part,
    int nP, int nG, float invP, float invG)
{
    const int i = blockIdx.x * BLK + threadIdx.x;
    float v = 0.f;
    if (i < nP + nG) {
        const unsigned int k = mins[i];
        const float d = (k == 0xFFFFFFFFu) ? 1.0e30f : fmaxf(0.f, key2f(k));
        v = d * (i < nP ? invP : invG);
    }
    #pragma unroll
    for (int o = 32; o > 0; o >>= 1) v += __shfl_xor(v, o);
    __shared__ float r[WPB];
    const int wid = threadIdx.x >> 6, lane = threadIdx.x & 63;
    if (lane == 0) r[wid] = v;
    __syncthreads();
    if (threadIdx.x == 0) part[blockIdx.x] = r[0] + r[1] + r[2] + r[3];
}

// Stage 2: one block, fixed-order deterministic sum of the partials.
__global__ __launch_bounds__(BLK) void chamfer_reduce2(
    const float* __restrict__ part, float* __restrict__ out, int nPart)
{
    float v = 0.f;
    for (int i = threadIdx.x; i < nPart; i += BLK) v += part[i];
    #pragma unroll
    for (int o = 32; o > 0; o >>= 1) v += __shfl_xor(v, o);
    __shared__ float r[WPB];
    const int wid = threadIdx.x >> 6, lane = threadIdx.x & 63;
    if (lane == 0) r[wid] = v;
    __syncthreads();
    if (threadIdx.x == 0) out[0] = r[0] + r[1] + r[2] + r[3];
}

extern "C" void kernel_launch(void* const* d_in, const int* in_sizes, int n_in,
                              void* d_out, int out_size, void* d_ws, size_t ws_size,
                              hipStream_t stream)
{
    const float* pred = (const float*)d_in[0];
    const float* gt   = (const float*)d_in[1];
    const int nP = in_sizes[0] / 3;
    const int nG = in_sizes[1] / 4;
    const int nTot = nP + nG;

    unsigned int* mins = (unsigned int*)d_ws;                       // nTot keys
    const int nPart = (nTot + BLK - 1) / BLK;                       // 157
    float* part = (float*)((char*)d_ws + (((size_t)nTot * 4 + 255) & ~(size_t)255));
    (void)ws_size; (void)n_in; (void)out_size;

    hipMemsetAsync(mins, 0xFF, (size_t)nTot * 4, stream);           // keys = +inf

    const int maxN = nP > nG ? nP : nG;
    const int tilesMax = (maxN + 31) / 32;                          // 625
    dim3 grid((tilesMax + TPB - 1) / TPB,                           // 79
              (maxN + CH_SLOTS - 1) / CH_SLOTS,                     // 32
              2);
    chamfer_mfma<<<grid, BLK, 0, stream>>>(pred, gt, mins, nP, nG);

    chamfer_reduce1<<<nPart, BLK, 0, stream>>>(mins, part, nP, nG,
                                               1.0f / (float)nP, 1.0f / (float)nG);
    chamfer_reduce2<<<1, BLK, 0, stream>>>(part, (float*)d_out, nPart);
}